// Round 1
// baseline (3589.144 us; speedup 1.0000x reference)
//
#include <hip/hip_runtime.h>
#include <math.h>

#define B_    32
#define N_    256
#define DIN   512
#define DOUT  2048
#define RANK_ 12
#define K_    16
#define HC    192
#define CD    1536
#define P1    192
#define P2    384

// ---------------- K1: z = [cls, mean, var] ----------------
__global__ void k_stats(const float* __restrict__ x, float* __restrict__ z) {
  int b = blockIdx.x, d = threadIdx.x;
  const float* xb = x + (size_t)b * N_ * DIN;
  float s = 0.f, s2 = 0.f;
  for (int n = 0; n < N_; ++n) {
    float t = xb[(size_t)n * DIN + d];
    s += t; s2 += t * t;
  }
  float mean = s * (1.0f / N_);
  float var = s2 * (1.0f / N_) - mean * mean;
  float* zb = z + (size_t)b * CD;
  zb[d] = xb[d];
  zb[DIN + d] = mean;
  zb[2 * DIN + d] = var;
}

// ---------------- K2: controller ----------------
__global__ void k_controller(const float* __restrict__ z, const float* __restrict__ W1,
                             const float* __restrict__ b1, const float* __restrict__ Wc,
                             const float* __restrict__ bc, const float* __restrict__ Wg,
                             const float* __restrict__ bg, float* __restrict__ coeff,
                             float* __restrict__ gate) {
  int b = blockIdx.x, j = threadIdx.x;
  __shared__ float zs[CD];
  __shared__ float hs[HC];
  const float* zb = z + (size_t)b * CD;
  for (int i = j; i < CD; i += HC) zs[i] = zb[i];
  __syncthreads();
  float acc = b1[j];
  for (int d = 0; d < CD; ++d) acc = fmaf(zs[d], W1[(size_t)d * HC + j], acc);
  // gelu (tanh approximation, jax.nn.gelu default)
  float x3 = acc * acc * acc;
  float hj = 0.5f * acc * (1.0f + tanhf(0.7978845608028654f * (acc + 0.044715f * x3)));
  hs[j] = hj;
  __syncthreads();
  if (j < K_) {
    float c = bc[j];
    for (int t = 0; t < HC; ++t) c = fmaf(hs[t], Wc[t * K_ + j], c);
    coeff[b * K_ + j] = c;
  } else if (j == K_) {
    float g = bg[0];
    for (int t = 0; t < HC; ++t) g = fmaf(hs[t], Wg[t], g);
    gate[b] = 1.0f / (1.0f + expf(-g));
  }
}

// ---------------- K3: repack bases: Lcat (2048x192), E[:,0:192]=Rcat ----------------
__global__ void k_copy_bases(const float* __restrict__ leftb, const float* __restrict__ rightb,
                             float* __restrict__ Lcat, float* __restrict__ E) {
  int idx = blockIdx.x * 256 + threadIdx.x;
  const int totL = DOUT * P1;
  const int totR = DIN * P1;
  if (idx < totL) {
    int m = idx / P1, j = idx - m * P1;
    int k = j / RANK_, r = j - k * RANK_;
    Lcat[idx] = leftb[((size_t)k * DOUT + m) * RANK_ + r];
  } else if (idx < totL + totR) {
    int i2 = idx - totL;
    int d = i2 / P1, j = i2 - d * P1;
    int k = j / RANK_, r = j - k * RANK_;
    E[(size_t)d * P2 + j] = rightb[((size_t)k * DIN + d) * RANK_ + r];
  }
}

// ---------------- generic TN GEMM: C[i,j] = sum_k A[k*lda+i]*B[k*ldb+j] ----------------
// requires M,N,K multiples of 32
__global__ __launch_bounds__(256) void k_gemm_tn(const float* __restrict__ A,
                                                 const float* __restrict__ B,
                                                 float* __restrict__ C,
                                                 int M, int N, int Kd, int lda, int ldb, int ldc) {
  __shared__ float As[32][33], Bs[32][33];
  int i0 = blockIdx.x * 32, j0 = blockIdx.y * 32;
  int t = threadIdx.x;
  int ii = t & 31, j4 = (t >> 5) * 4;
  float acc[4] = {0.f, 0.f, 0.f, 0.f};
  for (int kb = 0; kb < Kd; kb += 32) {
    for (int idx = t; idx < 1024; idx += 256) {
      int kk = idx >> 5, c = idx & 31;
      As[kk][c] = A[(size_t)(kb + kk) * lda + i0 + c];
      Bs[kk][c] = B[(size_t)(kb + kk) * ldb + j0 + c];
    }
    __syncthreads();
#pragma unroll 8
    for (int kk = 0; kk < 32; ++kk) {
      float a = As[kk][ii];
#pragma unroll
      for (int q = 0; q < 4; ++q) acc[q] = fmaf(a, Bs[kk][j4 + q], acc[q]);
    }
    __syncthreads();
  }
#pragma unroll
  for (int q = 0; q < 4; ++q) C[(size_t)(i0 + ii) * ldc + j0 + j4 + q] = acc[q];
}

// ---------------- K4b: per-k tangent norms from Gram blocks ----------------
__global__ void k_norms(const float* __restrict__ GLL, const float* __restrict__ GE,
                        float* __restrict__ norms) {
  int k = blockIdx.x, t = threadIdx.x;  // 64 threads
  float s1 = 0.f, s2 = 0.f, s3 = 0.f;
  for (int idx = t; idx < RANK_ * RANK_; idx += 64) {
    int r = idx / RANK_, s = idx - r * RANK_;
    int p = k * RANK_ + r, q = k * RANK_ + s;
    float gll = GLL[p * P1 + q];
    float grr = GE[p * P2 + q];
    float gpp = GE[(P1 + p) * P2 + (P1 + q)];
    float gpr = GE[(P1 + p) * P2 + q];
    float gprt = GE[(P1 + q) * P2 + p];
    s1 += gll * grr;
    s2 += gpp * grr;
    s3 += gpr * gprt;
  }
#pragma unroll
  for (int off = 32; off > 0; off >>= 1) {
    s1 += __shfl_down(s1, off);
    s2 += __shfl_down(s2, off);
    s3 += __shfl_down(s3, off);
  }
  if (t == 0) norms[k] = sqrtf(fmaxf(s1 - 0.5f * (s2 + s3), 0.0f));
}

// ---------------- K5: c' = coeff / max(norm,1e-6) ----------------
__global__ void k_cprime(const float* __restrict__ coeff, const float* __restrict__ norms,
                         float* __restrict__ cp) {
  int t = threadIdx.x;
  if (t < B_ * K_) {
    int k = t & 15;
    cp[t] = coeff[t] / fmaxf(norms[k], 1e-6f);
  }
}

// ---------------- K5b: assemble M0 (384x384) ----------------
__global__ void k_m0(const float* __restrict__ GLL, const float* __restrict__ GE,
                     float* __restrict__ M0) {
  int idx = blockIdx.x * 256 + threadIdx.x;
  if (idx >= P2 * P2) return;
  int p = idx / P2, q = idx - p * P2;
  float v;
  if (p < P1) {
    if (q < P1) v = GLL[p * P1 + q] - 0.75f * GE[(P1 + p) * P2 + (P1 + q)];
    else        v = -0.25f * GE[(P1 + p) * P2 + (q - P1)];
  } else {
    if (q < P1) v = -0.25f * GE[(P1 + q) * P2 + (p - P1)];
    else        v = 0.25f * GE[(p - P1) * P2 + (q - P1)];
  }
  M0[idx] = v;
}

// ---------------- K6: H_b = (E .* chat_b) @ M0   (batched 512x384x384) ----------------
__global__ __launch_bounds__(256) void k_H(const float* __restrict__ E, const float* __restrict__ M0,
                                           const float* __restrict__ cp, float* __restrict__ H) {
  int b = blockIdx.z;
  int i0 = blockIdx.x * 64, q0 = blockIdx.y * 64;
  int t = threadIdx.x;
  __shared__ float As[16][65], Bs[16][66];
  const float* cpb = cp + b * K_;
  float* Hb = H + (size_t)b * DIN * P2;
  int tx = t & 15, ty = t >> 4;
  float acc[4][4] = {};
  for (int p0 = 0; p0 < P2; p0 += 16) {
    for (int idx = t; idx < 1024; idx += 256) {
      int ii = idx >> 4, pp = idx & 15;
      int p = p0 + pp;
      int pk = (p >= P1 ? p - P1 : p) / RANK_;
      As[pp][ii] = E[(size_t)(i0 + ii) * P2 + p] * cpb[pk];
    }
    for (int idx = t; idx < 1024; idx += 256) {
      int pp = idx >> 6, qq = idx & 63;
      Bs[pp][qq] = M0[(size_t)(p0 + pp) * P2 + q0 + qq];
    }
    __syncthreads();
#pragma unroll
    for (int pp = 0; pp < 16; ++pp) {
      float a[4], bv[4];
#pragma unroll
      for (int u = 0; u < 4; ++u) a[u] = As[pp][ty * 4 + u];
#pragma unroll
      for (int u = 0; u < 4; ++u) bv[u] = Bs[pp][tx * 4 + u];
#pragma unroll
      for (int u = 0; u < 4; ++u)
#pragma unroll
        for (int v = 0; v < 4; ++v) acc[u][v] = fmaf(a[u], bv[v], acc[u][v]);
    }
    __syncthreads();
  }
#pragma unroll
  for (int u = 0; u < 4; ++u)
#pragma unroll
    for (int v = 0; v < 4; ++v)
      Hb[(size_t)(i0 + ty * 4 + u) * P2 + q0 + tx * 4 + v] = acc[u][v];
}

// ---------------- K7: G_b = I + H_b @ (E .* chat_b)^T  (batched NT 512x512x384) ----------------
__global__ __launch_bounds__(256) void k_G(const float* __restrict__ H, const float* __restrict__ E,
                                           const float* __restrict__ cp, float* __restrict__ G) {
  int b = blockIdx.z;
  int i0 = blockIdx.x * 64, j0 = blockIdx.y * 64;
  int t = threadIdx.x;
  __shared__ float As[16][65], Bs[16][65];
  const float* cpb = cp + b * K_;
  const float* Hb = H + (size_t)b * DIN * P2;
  float* Gb = G + (size_t)b * DIN * DIN;
  int tx = t & 15, ty = t >> 4;
  float acc[4][4] = {};
  for (int q0 = 0; q0 < P2; q0 += 16) {
    for (int idx = t; idx < 1024; idx += 256) {
      int ii = idx >> 4, qq = idx & 15;
      As[qq][ii] = Hb[(size_t)(i0 + ii) * P2 + q0 + qq];
    }
    for (int idx = t; idx < 1024; idx += 256) {
      int jj = idx >> 4, qq = idx & 15;
      int q = q0 + qq;
      int pk = (q >= P1 ? q - P1 : q) / RANK_;
      Bs[qq][jj] = E[(size_t)(j0 + jj) * P2 + q] * cpb[pk];
    }
    __syncthreads();
#pragma unroll
    for (int qq = 0; qq < 16; ++qq) {
      float a[4], bv[4];
#pragma unroll
      for (int u = 0; u < 4; ++u) a[u] = As[qq][ty * 4 + u];
#pragma unroll
      for (int u = 0; u < 4; ++u) bv[u] = Bs[qq][tx * 4 + u];
#pragma unroll
      for (int u = 0; u < 4; ++u)
#pragma unroll
        for (int v = 0; v < 4; ++v) acc[u][v] = fmaf(a[u], bv[v], acc[u][v]);
    }
    __syncthreads();
  }
#pragma unroll
  for (int u = 0; u < 4; ++u)
#pragma unroll
    for (int v = 0; v < 4; ++v) {
      int gi = i0 + ty * 4 + u, gj = j0 + tx * 4 + v;
      Gb[(size_t)gi * DIN + gj] = acc[u][v] + (gi == gj ? 1.0f : 0.0f);
    }
}

// ---------------- K8: batched in-place Cholesky (upper R, G = R^T R), one block per b ----------------
__global__ __launch_bounds__(256) void k_chol(float* __restrict__ G) {
  int b = blockIdx.x;
  float* Gb = G + (size_t)b * DIN * DIN;
  __shared__ float D[32][33];
  int t = threadIdx.x;
  for (int pnl = 0; pnl < 16; ++pnl) {
    int j0 = pnl * 32;
    int rem = DIN - j0 - 32;
    // load + factor diagonal block
    for (int idx = t; idx < 1024; idx += 256) {
      int i = idx >> 5, c = idx & 31;
      D[i][c] = Gb[(size_t)(j0 + i) * DIN + j0 + c];
    }
    __syncthreads();
    for (int jj = 0; jj < 32; ++jj) {
      if (t == 0) D[jj][jj] = sqrtf(fmaxf(D[jj][jj], 1e-30f));
      __syncthreads();
      float dinv = 1.0f / D[jj][jj];
      for (int c = jj + 1 + t; c < 32; c += 256) D[jj][c] *= dinv;
      __syncthreads();
      for (int idx = t; idx < 1024; idx += 256) {
        int i = idx >> 5, c = idx & 31;
        if (i > jj && c >= i) D[i][c] -= D[jj][i] * D[jj][c];
      }
      __syncthreads();
    }
    for (int idx = t; idx < 1024; idx += 256) {
      int i = idx >> 5, c = idx & 31;
      Gb[(size_t)(j0 + i) * DIN + j0 + c] = D[i][c];
    }
    // panel solve: R[J,c] = Rd^-T * A[J,c] for c >= j0+32  (each thread owns columns)
    for (int c = j0 + 32 + t; c < DIN; c += 256) {
      float a[32];
#pragma unroll
      for (int jj = 0; jj < 32; ++jj) a[jj] = Gb[(size_t)(j0 + jj) * DIN + c];
#pragma unroll
      for (int jj = 0; jj < 32; ++jj) {
        float val = a[jj];
        for (int tt = 0; tt < jj; ++tt) val -= D[tt][jj] * a[tt];
        val /= D[jj][jj];
        a[jj] = val;
        Gb[(size_t)(j0 + jj) * DIN + c] = val;
      }
    }
    __syncthreads();
    // trailing update: G[i,c] -= panel^T panel (upper only), panel read from global (L2)
    if (rem > 0) {
      int nt = rem >> 2;
      for (int tile = t; tile < nt * nt; tile += 256) {
        int ti = tile % nt, tc = tile / nt;
        int i0r = ti * 4, c0r = tc * 4;
        if (c0r + 3 < i0r) continue;
        int gi0 = j0 + 32 + i0r, gc0 = j0 + 32 + c0r;
        float acc[4][4] = {};
#pragma unroll 8
        for (int jj = 0; jj < 32; ++jj) {
          const float* prow = &Gb[(size_t)(j0 + jj) * DIN];
          float4 av = *(const float4*)(prow + gi0);
          float4 cv = *(const float4*)(prow + gc0);
          float aa[4] = {av.x, av.y, av.z, av.w};
          float cc[4] = {cv.x, cv.y, cv.z, cv.w};
#pragma unroll
          for (int u = 0; u < 4; ++u)
#pragma unroll
            for (int v = 0; v < 4; ++v) acc[u][v] = fmaf(aa[u], cc[v], acc[u][v]);
        }
#pragma unroll
        for (int u = 0; u < 4; ++u)
#pragma unroll
          for (int v = 0; v < 4; ++v) {
            int gi = gi0 + u, gc = gc0 + v;
            if (gc >= gi) Gb[(size_t)gi * DIN + gc] -= acc[u][v];
          }
      }
    }
    __syncthreads();
  }
}

// ---------------- K9: y = x @ R^-T  (backward substitution, 16 rows per block) ----------------
__global__ __launch_bounds__(256) void k_trisolve(const float* __restrict__ x,
                                                  const float* __restrict__ G,
                                                  float* __restrict__ y) {
  int rg = blockIdx.x, b = blockIdx.y;
  const float* R = G + (size_t)b * DIN * DIN;
  __shared__ float Y[16][516];
  int t = threadIdx.x;
  const float* xb = x + ((size_t)b * N_ + rg * 16) * DIN;
  for (int idx = t; idx < 16 * DIN; idx += 256) {
    int r = idx >> 9, c = idx & 511;
    Y[r][c] = xb[(size_t)r * DIN + c];
  }
  __syncthreads();
  for (int pnl = 15; pnl >= 0; --pnl) {
    int j0 = pnl * 32;
    for (int jj = 31; jj >= 0; --jj) {
      int j = j0 + jj;
      float rinv = 1.0f / R[(size_t)j * DIN + j];
      if (t < 16) Y[t][j] *= rinv;
      __syncthreads();
      for (int idx = t; idx < 16 * jj; idx += 256) {
        int r = idx & 15, cc = idx >> 4;
        Y[r][j0 + cc] -= Y[r][j] * R[(size_t)(j0 + cc) * DIN + j];
      }
      __syncthreads();
    }
    if (j0 > 0) {
      int ntc = j0 >> 2;
      for (int tile = t; tile < 4 * ntc; tile += 256) {
        int tr = tile & 3, tc = tile >> 2;
        int r0 = tr * 4, c0 = tc * 4;
        float acc[4][4] = {};
#pragma unroll 4
        for (int jj = 0; jj < 32; ++jj) {
          float aa[4], bb[4];
#pragma unroll
          for (int u = 0; u < 4; ++u) aa[u] = Y[r0 + u][j0 + jj];
#pragma unroll
          for (int v = 0; v < 4; ++v) bb[v] = R[(size_t)(c0 + v) * DIN + j0 + jj];
#pragma unroll
          for (int u = 0; u < 4; ++u)
#pragma unroll
            for (int v = 0; v < 4; ++v) acc[u][v] = fmaf(aa[u], bb[v], acc[u][v]);
        }
#pragma unroll
        for (int u = 0; u < 4; ++u)
#pragma unroll
          for (int v = 0; v < 4; ++v) Y[r0 + u][c0 + v] -= acc[u][v];
      }
    }
    __syncthreads();
  }
  float* yb = y + ((size_t)b * N_ + rg * 16) * DIN;
  for (int idx = t; idx < 16 * DIN; idx += 256) {
    int r = idx >> 9, c = idx & 511;
    yb[(size_t)r * DIN + c] = Y[r][c];
  }
}

// ---------------- K10: yE_b = y_b @ E  (batched NN 256x384x512) ----------------
__global__ __launch_bounds__(256) void k_yE(const float* __restrict__ y, const float* __restrict__ E,
                                            float* __restrict__ yE) {
  int b = blockIdx.z;
  int n0 = blockIdx.x * 64, j0 = blockIdx.y * 64;
  const float* yb = y + (size_t)b * N_ * DIN;
  float* yEb = yE + (size_t)b * N_ * P2;
  __shared__ float As[16][65], Bs[16][66];
  int t = threadIdx.x;
  int tx = t & 15, ty = t >> 4;
  float acc[4][4] = {};
  for (int k0 = 0; k0 < DIN; k0 += 16) {
    for (int idx = t; idx < 1024; idx += 256) {
      int nn = idx >> 4, kk = idx & 15;
      As[kk][nn] = yb[(size_t)(n0 + nn) * DIN + k0 + kk];
    }
    for (int idx = t; idx < 1024; idx += 256) {
      int kk = idx >> 6, jj = idx & 63;
      Bs[kk][jj] = E[(size_t)(k0 + kk) * P2 + j0 + jj];
    }
    __syncthreads();
#pragma unroll
    for (int kk = 0; kk < 16; ++kk) {
      float a[4], bv[4];
#pragma unroll
      for (int u = 0; u < 4; ++u) a[u] = As[kk][ty * 4 + u];
#pragma unroll
      for (int v = 0; v < 4; ++v) bv[v] = Bs[kk][tx * 4 + v];
#pragma unroll
      for (int u = 0; u < 4; ++u)
#pragma unroll
        for (int v = 0; v < 4; ++v) acc[u][v] = fmaf(a[u], bv[v], acc[u][v]);
    }
    __syncthreads();
  }
#pragma unroll
  for (int u = 0; u < 4; ++u)
#pragma unroll
    for (int v = 0; v < 4; ++v)
      yEb[(size_t)(n0 + ty * 4 + u) * P2 + j0 + tx * 4 + v] = acc[u][v];
}

// ---------------- K11: build u (in-place in yE, halves swapped+scaled) and v ----------------
__global__ void k_uv(const float* __restrict__ cp, const float* __restrict__ gate,
                     float* __restrict__ yE, float* __restrict__ v) {
  int idx = blockIdx.x * 256 + threadIdx.x;
  if (idx >= B_ * N_ * P1) return;
  int q = idx % P1;
  int bn = idx / P1;
  int b = bn / N_;
  int k = q / RANK_;
  float cc = cp[b * K_ + k];
  size_t base = (size_t)bn * P2;
  float yR = yE[base + q];
  float yP = yE[base + P1 + q];
  yE[base + q] = 0.5f * cc * yP;       // u1 (pairs Rcat^T)
  yE[base + P1 + q] = 0.5f * cc * yR;  // u2 (pairs Pcat^T)
  v[(size_t)bn * P1 + q] = gate[b] * cc * yR;
}

// ---------------- K12: w = gate*(y - x - u@E^T)  (batched NT, in-place into y) ----------------
__global__ __launch_bounds__(256) void k_w(const float* __restrict__ u, const float* __restrict__ E,
                                           const float* __restrict__ x, const float* __restrict__ gate,
                                           float* __restrict__ yio) {
  int b = blockIdx.z;
  int n0 = blockIdx.x * 64, d0 = blockIdx.y * 64;
  const float* ub = u + (size_t)b * N_ * P2;
  __shared__ float As[16][65], Bs[16][65];
  int t = threadIdx.x;
  int tx = t & 15, ty = t >> 4;
  float acc[4][4] = {};
  for (int q0 = 0; q0 < P2; q0 += 16) {
    for (int idx = t; idx < 1024; idx += 256) {
      int nn = idx >> 4, qq = idx & 15;
      As[qq][nn] = ub[(size_t)(n0 + nn) * P2 + q0 + qq];
    }
    for (int idx = t; idx < 1024; idx += 256) {
      int dd = idx >> 4, qq = idx & 15;
      Bs[qq][dd] = E[(size_t)(d0 + dd) * P2 + q0 + qq];
    }
    __syncthreads();
#pragma unroll
    for (int qq = 0; qq < 16; ++qq) {
      float a[4], bv[4];
#pragma unroll
      for (int u2 = 0; u2 < 4; ++u2) a[u2] = As[qq][ty * 4 + u2];
#pragma unroll
      for (int v2 = 0; v2 < 4; ++v2) bv[v2] = Bs[qq][tx * 4 + v2];
#pragma unroll
      for (int u2 = 0; u2 < 4; ++u2)
#pragma unroll
        for (int v2 = 0; v2 < 4; ++v2) acc[u2][v2] = fmaf(a[u2], bv[v2], acc[u2][v2]);
    }
    __syncthreads();
  }
  float gt = gate[b];
#pragma unroll
  for (int u2 = 0; u2 < 4; ++u2)
#pragma unroll
    for (int v2 = 0; v2 < 4; ++v2) {
      size_t gi = ((size_t)b * N_ + n0 + ty * 4 + u2) * DIN + d0 + tx * 4 + v2;
      yio[gi] = gt * (yio[gi] - x[gi] - acc[u2][v2]);
    }
}

// ---------------- K13: fused output GEMM: out = [x|w|v] @ [W;U0;Lcat]^T + bias ----------------
__global__ __launch_bounds__(256) void k_final(const float* __restrict__ x, const float* __restrict__ wbuf,
                                               const float* __restrict__ vbuf, const float* __restrict__ Wsh,
                                               const float* __restrict__ U0, const float* __restrict__ Lcat,
                                               const float* __restrict__ bias, float* __restrict__ out) {
  __shared__ __align__(16) float As[16][132];
  __shared__ __align__(16) float Bs[16][132];
  int c0 = blockIdx.x * 128;
  int r0 = blockIdx.y * 128;
  int t = threadIdx.x;
  int tx = t & 15, ty = t >> 4;
  int lrow = t >> 1, lk8 = (t & 1) << 3;
  float acc[8][8] = {};
  for (int k0 = 0; k0 < 1216; k0 += 16) {
    const float* Aseg; const float* Bseg; int ksz, kloc;
    if (k0 < 512)        { Aseg = x;    Bseg = Wsh;  ksz = 512; kloc = k0; }
    else if (k0 < 1024)  { Aseg = wbuf; Bseg = U0;   ksz = 512; kloc = k0 - 512; }
    else                 { Aseg = vbuf; Bseg = Lcat; ksz = 192; kloc = k0 - 1024; }
    const float* pa = Aseg + (size_t)(r0 + lrow) * ksz + kloc + lk8;
    const float* pb = Bseg + (size_t)(c0 + lrow) * ksz + kloc + lk8;
    float4 a0 = *(const float4*)pa;
    float4 a1 = *(const float4*)(pa + 4);
    float4 b0 = *(const float4*)pb;
    float4 b1 = *(const float4*)(pb + 4);
    __syncthreads();
    As[lk8 + 0][lrow] = a0.x; As[lk8 + 1][lrow] = a0.y; As[lk8 + 2][lrow] = a0.z; As[lk8 + 3][lrow] = a0.w;
    As[lk8 + 4][lrow] = a1.x; As[lk8 + 5][lrow] = a1.y; As[lk8 + 6][lrow] = a1.z; As[lk8 + 7][lrow] = a1.w;
    Bs[lk8 + 0][lrow] = b0.x; Bs[lk8 + 1][lrow] = b0.y; Bs[lk8 + 2][lrow] = b0.z; Bs[lk8 + 3][lrow] = b0.w;
    Bs[lk8 + 4][lrow] = b1.x; Bs[lk8 + 5][lrow] = b1.y; Bs[lk8 + 6][lrow] = b1.z; Bs[lk8 + 7][lrow] = b1.w;
    __syncthreads();
#pragma unroll
    for (int kk = 0; kk < 16; ++kk) {
      float4 av0 = *(const float4*)&As[kk][ty * 8];
      float4 av1 = *(const float4*)&As[kk][ty * 8 + 4];
      float4 bv0 = *(const float4*)&Bs[kk][tx * 8];
      float4 bv1 = *(const float4*)&Bs[kk][tx * 8 + 4];
      float aa[8] = {av0.x, av0.y, av0.z, av0.w, av1.x, av1.y, av1.z, av1.w};
      float bb[8] = {bv0.x, bv0.y, bv0.z, bv0.w, bv1.x, bv1.y, bv1.z, bv1.w};
#pragma unroll
      for (int u2 = 0; u2 < 8; ++u2)
#pragma unroll
        for (int v2 = 0; v2 < 8; ++v2) acc[u2][v2] = fmaf(aa[u2], bb[v2], acc[u2][v2]);
    }
  }
#pragma unroll
  for (int u2 = 0; u2 < 8; ++u2) {
    size_t ro = (size_t)(r0 + ty * 8 + u2) * DOUT + c0 + tx * 8;
#pragma unroll
    for (int v2 = 0; v2 < 8; ++v2) out[ro + v2] = acc[u2][v2] + bias[c0 + tx * 8 + v2];
  }
}

extern "C" void kernel_launch(void* const* d_in, const int* in_sizes, int n_in,
                              void* d_out, int out_size, void* d_ws, size_t ws_size,
                              hipStream_t stream) {
  (void)in_sizes; (void)n_in; (void)out_size; (void)ws_size;
  const float* x     = (const float*)d_in[0];
  const float* Wsh   = (const float*)d_in[1];
  const float* bias  = (const float*)d_in[2];
  const float* U0    = (const float*)d_in[3];
  const float* leftb = (const float*)d_in[4];
  const float* rightb= (const float*)d_in[5];
  const float* W1    = (const float*)d_in[6];
  const float* b1    = (const float*)d_in[7];
  const float* Wc    = (const float*)d_in[8];
  const float* bc    = (const float*)d_in[9];
  const float* Wg    = (const float*)d_in[10];
  const float* bg    = (const float*)d_in[11];
  float* out = (float*)d_out;

  float* wsf = (float*)d_ws;
  size_t o = 0;
  float* z     = wsf + o; o += B_ * CD;          // 49152
  float* coeff = wsf + o; o += B_ * K_;          // 512
  float* gate  = wsf + o; o += 64;
  float* norms = wsf + o; o += 64;
  float* cp    = wsf + o; o += B_ * K_;
  float* Lcat  = wsf + o; o += (size_t)DOUT * P1; // 393216
  float* E     = wsf + o; o += (size_t)DIN * P2;  // 196608
  float* GLL   = wsf + o; o += P1 * P1;           // 36864
  float* GE    = wsf + o; o += P2 * P2;           // 147456
  float* M0    = wsf + o; o += P2 * P2;           // 147456
  float* v     = wsf + o; o += (size_t)B_ * N_ * P1;  // 1572864
  float* y     = wsf + o; o += (size_t)B_ * N_ * DIN; // 4194304
  float* yE    = wsf + o; o += (size_t)B_ * N_ * P2;  // 3145728
  // H (B*512*384 = 6291456 floats) aliases [y, y+y_len+yE_len): dead before y is written
  float* H = y;
  // G (32 x 512 x 512 = 8388608 floats = 33.5MB) lives in d_out; fully overwritten by k_final
  float* G = out;

  k_stats<<<B_, DIN, 0, stream>>>(x, z);
  k_controller<<<B_, HC, 0, stream>>>(z, W1, b1, Wc, bc, Wg, bg, coeff, gate);
  k_copy_bases<<<(DOUT * P1 + DIN * P1 + 255) / 256, 256, 0, stream>>>(leftb, rightb, Lcat, E);
  // Pcat = U0^T Lcat -> E[:,192:384]
  k_gemm_tn<<<dim3(DIN / 32, P1 / 32), 256, 0, stream>>>(U0, Lcat, E + P1, DIN, P1, DOUT, DIN, P1, P2);
  // GLL = Lcat^T Lcat
  k_gemm_tn<<<dim3(P1 / 32, P1 / 32), 256, 0, stream>>>(Lcat, Lcat, GLL, P1, P1, DOUT, P1, P1, P1);
  // GE = E^T E  (blocks: GRR, GRP; GPR, GPP)
  k_gemm_tn<<<dim3(P2 / 32, P2 / 32), 256, 0, stream>>>(E, E, GE, P2, P2, DIN, P2, P2, P2);
  k_norms<<<K_, 64, 0, stream>>>(GLL, GE, norms);
  k_cprime<<<1, 512, 0, stream>>>(coeff, norms, cp);
  k_m0<<<(P2 * P2 + 255) / 256, 256, 0, stream>>>(GLL, GE, M0);
  k_H<<<dim3(DIN / 64, P2 / 64, B_), 256, 0, stream>>>(E, M0, cp, H);
  k_G<<<dim3(DIN / 64, DIN / 64, B_), 256, 0, stream>>>(H, E, cp, G);
  k_chol<<<B_, 256, 0, stream>>>(G);
  k_trisolve<<<dim3(16, B_), 256, 0, stream>>>(x, G, y);
  k_yE<<<dim3(N_ / 64, P2 / 64, B_), 256, 0, stream>>>(y, E, yE);
  k_uv<<<(B_ * N_ * P1 + 255) / 256, 256, 0, stream>>>(cp, gate, yE, v);
  k_w<<<dim3(N_ / 64, DIN / 64, B_), 256, 0, stream>>>(yE, E, x, gate, y);
  k_final<<<dim3(DOUT / 128, (B_ * N_) / 128), 256, 0, stream>>>(x, y, v, Wsh, U0, Lcat, bias, out);
}

// Round 2
// 2573.571 us; speedup vs baseline: 1.3946x; 1.3946x over previous
//
#include <hip/hip_runtime.h>
#include <math.h>

#define B_    32
#define N_    256
#define DIN   512
#define DOUT  2048
#define RANK_ 12
#define K_    16
#define HC    192
#define CD    1536
#define P1    192
#define P2    384

// ---------------- K1: z = [cls, mean, var] ----------------
__global__ void k_stats(const float* __restrict__ x, float* __restrict__ z) {
  int b = blockIdx.x, d = threadIdx.x;
  const float* xb = x + (size_t)b * N_ * DIN;
  float s = 0.f, s2 = 0.f;
  for (int n = 0; n < N_; ++n) {
    float t = xb[(size_t)n * DIN + d];
    s += t; s2 += t * t;
  }
  float mean = s * (1.0f / N_);
  float var = s2 * (1.0f / N_) - mean * mean;
  float* zb = z + (size_t)b * CD;
  zb[d] = xb[d];
  zb[DIN + d] = mean;
  zb[2 * DIN + d] = var;
}

// ---------------- K2: controller ----------------
__global__ void k_controller(const float* __restrict__ z, const float* __restrict__ W1,
                             const float* __restrict__ b1, const float* __restrict__ Wc,
                             const float* __restrict__ bc, const float* __restrict__ Wg,
                             const float* __restrict__ bg, float* __restrict__ coeff,
                             float* __restrict__ gate) {
  int b = blockIdx.x, j = threadIdx.x;
  __shared__ float zs[CD];
  __shared__ float hs[HC];
  const float* zb = z + (size_t)b * CD;
  for (int i = j; i < CD; i += HC) zs[i] = zb[i];
  __syncthreads();
  float acc = b1[j];
  for (int d = 0; d < CD; ++d) acc = fmaf(zs[d], W1[(size_t)d * HC + j], acc);
  // gelu (tanh approximation, jax.nn.gelu default)
  float x3 = acc * acc * acc;
  float hj = 0.5f * acc * (1.0f + tanhf(0.7978845608028654f * (acc + 0.044715f * x3)));
  hs[j] = hj;
  __syncthreads();
  if (j < K_) {
    float c = bc[j];
    for (int t = 0; t < HC; ++t) c = fmaf(hs[t], Wc[t * K_ + j], c);
    coeff[b * K_ + j] = c;
  } else if (j == K_) {
    float g = bg[0];
    for (int t = 0; t < HC; ++t) g = fmaf(hs[t], Wg[t], g);
    gate[b] = 1.0f / (1.0f + expf(-g));
  }
}

// ---------------- K3: repack bases: Lcat (2048x192), E[:,0:192]=Rcat ----------------
__global__ void k_copy_bases(const float* __restrict__ leftb, const float* __restrict__ rightb,
                             float* __restrict__ Lcat, float* __restrict__ E) {
  int idx = blockIdx.x * 256 + threadIdx.x;
  const int totL = DOUT * P1;
  const int totR = DIN * P1;
  if (idx < totL) {
    int m = idx / P1, j = idx - m * P1;
    int k = j / RANK_, r = j - k * RANK_;
    Lcat[idx] = leftb[((size_t)k * DOUT + m) * RANK_ + r];
  } else if (idx < totL + totR) {
    int i2 = idx - totL;
    int d = i2 / P1, j = i2 - d * P1;
    int k = j / RANK_, r = j - k * RANK_;
    E[(size_t)d * P2 + j] = rightb[((size_t)k * DIN + d) * RANK_ + r];
  }
}

// ---------------- generic TN GEMM: C[i,j] = sum_k A[k*lda+i]*B[k*ldb+j] ----------------
// requires M,N,K multiples of 32
__global__ __launch_bounds__(256) void k_gemm_tn(const float* __restrict__ A,
                                                 const float* __restrict__ B,
                                                 float* __restrict__ C,
                                                 int M, int N, int Kd, int lda, int ldb, int ldc) {
  __shared__ float As[32][33], Bs[32][33];
  int i0 = blockIdx.x * 32, j0 = blockIdx.y * 32;
  int t = threadIdx.x;
  int ii = t & 31, j4 = (t >> 5) * 4;
  float acc[4] = {0.f, 0.f, 0.f, 0.f};
  for (int kb = 0; kb < Kd; kb += 32) {
    for (int idx = t; idx < 1024; idx += 256) {
      int kk = idx >> 5, c = idx & 31;
      As[kk][c] = A[(size_t)(kb + kk) * lda + i0 + c];
      Bs[kk][c] = B[(size_t)(kb + kk) * ldb + j0 + c];
    }
    __syncthreads();
#pragma unroll 8
    for (int kk = 0; kk < 32; ++kk) {
      float a = As[kk][ii];
#pragma unroll
      for (int q = 0; q < 4; ++q) acc[q] = fmaf(a, Bs[kk][j4 + q], acc[q]);
    }
    __syncthreads();
  }
#pragma unroll
  for (int q = 0; q < 4; ++q) C[(size_t)(i0 + ii) * ldc + j0 + j4 + q] = acc[q];
}

// ---------------- K4b: per-k tangent norms from Gram blocks ----------------
__global__ void k_norms(const float* __restrict__ GLL, const float* __restrict__ GE,
                        float* __restrict__ norms) {
  int k = blockIdx.x, t = threadIdx.x;  // 64 threads
  float s1 = 0.f, s2 = 0.f, s3 = 0.f;
  for (int idx = t; idx < RANK_ * RANK_; idx += 64) {
    int r = idx / RANK_, s = idx - r * RANK_;
    int p = k * RANK_ + r, q = k * RANK_ + s;
    float gll = GLL[p * P1 + q];
    float grr = GE[p * P2 + q];
    float gpp = GE[(P1 + p) * P2 + (P1 + q)];
    float gpr = GE[(P1 + p) * P2 + q];
    float gprt = GE[(P1 + q) * P2 + p];
    s1 += gll * grr;
    s2 += gpp * grr;
    s3 += gpr * gprt;
  }
#pragma unroll
  for (int off = 32; off > 0; off >>= 1) {
    s1 += __shfl_down(s1, off);
    s2 += __shfl_down(s2, off);
    s3 += __shfl_down(s3, off);
  }
  if (t == 0) norms[k] = sqrtf(fmaxf(s1 - 0.5f * (s2 + s3), 0.0f));
}

// ---------------- K5: c' = coeff / max(norm,1e-6) ----------------
__global__ void k_cprime(const float* __restrict__ coeff, const float* __restrict__ norms,
                         float* __restrict__ cp) {
  int t = threadIdx.x;
  if (t < B_ * K_) {
    int k = t & 15;
    cp[t] = coeff[t] / fmaxf(norms[k], 1e-6f);
  }
}

// ---------------- K5b: assemble M0 (384x384) ----------------
__global__ void k_m0(const float* __restrict__ GLL, const float* __restrict__ GE,
                     float* __restrict__ M0) {
  int idx = blockIdx.x * 256 + threadIdx.x;
  if (idx >= P2 * P2) return;
  int p = idx / P2, q = idx - p * P2;
  float v;
  if (p < P1) {
    if (q < P1) v = GLL[p * P1 + q] - 0.75f * GE[(P1 + p) * P2 + (P1 + q)];
    else        v = -0.25f * GE[(P1 + p) * P2 + (q - P1)];
  } else {
    if (q < P1) v = -0.25f * GE[(P1 + q) * P2 + (p - P1)];
    else        v = 0.25f * GE[(p - P1) * P2 + (q - P1)];
  }
  M0[idx] = v;
}

// ---------------- K6: H_b = (E .* chat_b) @ M0   (batched 512x384x384) ----------------
__global__ __launch_bounds__(256) void k_H(const float* __restrict__ E, const float* __restrict__ M0,
                                           const float* __restrict__ cp, float* __restrict__ H) {
  int b = blockIdx.z;
  int i0 = blockIdx.x * 64, q0 = blockIdx.y * 64;
  int t = threadIdx.x;
  __shared__ float As[16][65], Bs[16][66];
  const float* cpb = cp + b * K_;
  float* Hb = H + (size_t)b * DIN * P2;
  int tx = t & 15, ty = t >> 4;
  float acc[4][4] = {};
  for (int p0 = 0; p0 < P2; p0 += 16) {
    for (int idx = t; idx < 1024; idx += 256) {
      int ii = idx >> 4, pp = idx & 15;
      int p = p0 + pp;
      int pk = (p >= P1 ? p - P1 : p) / RANK_;
      As[pp][ii] = E[(size_t)(i0 + ii) * P2 + p] * cpb[pk];
    }
    for (int idx = t; idx < 1024; idx += 256) {
      int pp = idx >> 6, qq = idx & 63;
      Bs[pp][qq] = M0[(size_t)(p0 + pp) * P2 + q0 + qq];
    }
    __syncthreads();
#pragma unroll
    for (int pp = 0; pp < 16; ++pp) {
      float a[4], bv[4];
#pragma unroll
      for (int u = 0; u < 4; ++u) a[u] = As[pp][ty * 4 + u];
#pragma unroll
      for (int u = 0; u < 4; ++u) bv[u] = Bs[pp][tx * 4 + u];
#pragma unroll
      for (int u = 0; u < 4; ++u)
#pragma unroll
        for (int v = 0; v < 4; ++v) acc[u][v] = fmaf(a[u], bv[v], acc[u][v]);
    }
    __syncthreads();
  }
#pragma unroll
  for (int u = 0; u < 4; ++u)
#pragma unroll
    for (int v = 0; v < 4; ++v)
      Hb[(size_t)(i0 + ty * 4 + u) * P2 + q0 + tx * 4 + v] = acc[u][v];
}

// ---------------- K7: G_b = I + H_b @ (E .* chat_b)^T  (batched NT 512x512x384) ----------------
__global__ __launch_bounds__(256) void k_G(const float* __restrict__ H, const float* __restrict__ E,
                                           const float* __restrict__ cp, float* __restrict__ G) {
  int b = blockIdx.z;
  int i0 = blockIdx.x * 64, j0 = blockIdx.y * 64;
  int t = threadIdx.x;
  __shared__ float As[16][65], Bs[16][65];
  const float* cpb = cp + b * K_;
  const float* Hb = H + (size_t)b * DIN * P2;
  float* Gb = G + (size_t)b * DIN * DIN;
  int tx = t & 15, ty = t >> 4;
  float acc[4][4] = {};
  for (int q0 = 0; q0 < P2; q0 += 16) {
    for (int idx = t; idx < 1024; idx += 256) {
      int ii = idx >> 4, qq = idx & 15;
      As[qq][ii] = Hb[(size_t)(i0 + ii) * P2 + q0 + qq];
    }
    for (int idx = t; idx < 1024; idx += 256) {
      int jj = idx >> 4, qq = idx & 15;
      int q = q0 + qq;
      int pk = (q >= P1 ? q - P1 : q) / RANK_;
      Bs[qq][jj] = E[(size_t)(j0 + jj) * P2 + q] * cpb[pk];
    }
    __syncthreads();
#pragma unroll
    for (int qq = 0; qq < 16; ++qq) {
      float a[4], bv[4];
#pragma unroll
      for (int u = 0; u < 4; ++u) a[u] = As[qq][ty * 4 + u];
#pragma unroll
      for (int u = 0; u < 4; ++u) bv[u] = Bs[qq][tx * 4 + u];
#pragma unroll
      for (int u = 0; u < 4; ++u)
#pragma unroll
        for (int v = 0; v < 4; ++v) acc[u][v] = fmaf(a[u], bv[v], acc[u][v]);
    }
    __syncthreads();
  }
#pragma unroll
  for (int u = 0; u < 4; ++u)
#pragma unroll
    for (int v = 0; v < 4; ++v) {
      int gi = i0 + ty * 4 + u, gj = j0 + tx * 4 + v;
      Gb[(size_t)gi * DIN + gj] = acc[u][v] + (gi == gj ? 1.0f : 0.0f);
    }
}

// ---------------- K8a: panel step — redundant 64x64 diag factor + panel solve ----------------
// grid (nt+1, B_), 64 threads (one wave). role 0 writes diag; role r>=1 solves col tile r-1.
__global__ __launch_bounds__(64) void k_chol_dp(float* __restrict__ G, int j0) {
  int b = blockIdx.y;
  int role = blockIdx.x;
  float* Gb = G + (size_t)b * DIN * DIN;
  __shared__ float D[64][65];
  __shared__ float dinv[64];
  int t = threadIdx.x;
  // load diag block (only upper part is valid/used)
#pragma unroll 8
  for (int i = 0; i < 64; ++i) D[i][t] = Gb[(size_t)(j0 + i) * DIN + j0 + t];
  __syncthreads();
  for (int j = 0; j < 64; ++j) {
    if (t == j) D[j][j] = sqrtf(fmaxf(D[j][j], 1e-30f));
    __syncthreads();
    float djj = D[j][j];
    if (t > j) D[j][t] /= djj;
    __syncthreads();
    if (t > j) {
      float djt = D[j][t];
      for (int i = j + 1; i <= t; ++i) D[i][t] -= D[j][i] * djt;
    }
    __syncthreads();
  }
  dinv[t] = 1.0f / D[t][t];
  __syncthreads();
  if (role == 0) {
#pragma unroll 8
    for (int i = 0; i < 64; ++i)
      if (t >= i) Gb[(size_t)(j0 + i) * DIN + j0 + t] = D[i][t];
  } else {
    int c = j0 + 64 + (role - 1) * 64 + t;
    float a[64];
#pragma unroll
    for (int i = 0; i < 64; ++i) a[i] = Gb[(size_t)(j0 + i) * DIN + c];
#pragma unroll
    for (int jj = 0; jj < 64; ++jj) {
      float val = a[jj];
      for (int tt = 0; tt < jj; ++tt) val -= D[tt][jj] * a[tt];
      a[jj] = val * dinv[jj];
    }
#pragma unroll
    for (int i = 0; i < 64; ++i) Gb[(size_t)(j0 + i) * DIN + c] = a[i];
  }
}

// ---------------- K8b: trailing update C -= P^T P over 64x64 tile pairs ----------------
// grid (nt*(nt+1)/2, B_), 256 threads.
__global__ __launch_bounds__(256) void k_chol_tr(float* __restrict__ G, int j0, int nt) {
  int b = blockIdx.y;
  int pi = blockIdx.x;
  // decode pair (ti <= tc) over triangle of size nt
  int ti = 0, accum = 0;
  while (pi >= accum + (nt - ti)) { accum += nt - ti; ++ti; }
  int tc = ti + (pi - accum);
  float* Gb = G + (size_t)b * DIN * DIN;
  __shared__ float As[64][65], Bs[64][65];
  int t = threadIdx.x;
  int ibase = j0 + 64 + ti * 64, cbase = j0 + 64 + tc * 64;
  for (int idx = t; idx < 4096; idx += 256) {
    int j = idx >> 6, c = idx & 63;
    As[j][c] = Gb[(size_t)(j0 + j) * DIN + ibase + c];
    Bs[j][c] = Gb[(size_t)(j0 + j) * DIN + cbase + c];
  }
  __syncthreads();
  int tx = t & 15, ty = t >> 4;
  float acc[4][4] = {};
#pragma unroll 8
  for (int k = 0; k < 64; ++k) {
    float a[4], bv[4];
#pragma unroll
    for (int u = 0; u < 4; ++u) a[u] = As[k][ty * 4 + u];
#pragma unroll
    for (int v = 0; v < 4; ++v) bv[v] = Bs[k][tx * 4 + v];
#pragma unroll
    for (int u = 0; u < 4; ++u)
#pragma unroll
      for (int v = 0; v < 4; ++v) acc[u][v] = fmaf(a[u], bv[v], acc[u][v]);
  }
#pragma unroll
  for (int u = 0; u < 4; ++u) {
    size_t ro = (size_t)(ibase + ty * 4 + u) * DIN + cbase + tx * 4;
#pragma unroll
    for (int v = 0; v < 4; ++v) Gb[ro + v] -= acc[u][v];
  }
}

// ---------------- K9: blocked trisolve panel: y[:,P] = (x[:,P] - y[:,>P] @ R[P,>P]^T) R_PP^-T ----
// launched backward over panels. grid (N_/64, B_), 256 threads.
__global__ __launch_bounds__(256) void k_tri(const float* __restrict__ x, const float* __restrict__ G,
                                             float* __restrict__ y, int j0) {
  int b = blockIdx.y;
  int n0 = blockIdx.x * 64;
  const float* R = G + (size_t)b * DIN * DIN;
  const float* xb = x + (size_t)b * N_ * DIN;
  float* yb = y + (size_t)b * N_ * DIN;
  __shared__ float As[16][65], Bs[16][65];
  __shared__ float Yt[64][65];
  __shared__ float Rp[64][65];
  int t = threadIdx.x;
  int tx = t & 15, ty = t >> 4;
  float acc[4][4] = {};
  for (int k0 = j0 + 64; k0 < DIN; k0 += 16) {
    for (int idx = t; idx < 1024; idx += 256) {
      int nn = idx >> 4, kk = idx & 15;
      As[kk][nn] = yb[(size_t)(n0 + nn) * DIN + k0 + kk];
      Bs[kk][nn] = R[(size_t)(j0 + nn) * DIN + k0 + kk];
    }
    __syncthreads();
#pragma unroll
    for (int kk = 0; kk < 16; ++kk) {
      float a[4], bv[4];
#pragma unroll
      for (int u = 0; u < 4; ++u) a[u] = As[kk][ty * 4 + u];
#pragma unroll
      for (int v = 0; v < 4; ++v) bv[v] = Bs[kk][tx * 4 + v];
#pragma unroll
      for (int u = 0; u < 4; ++u)
#pragma unroll
        for (int v = 0; v < 4; ++v) acc[u][v] = fmaf(a[u], bv[v], acc[u][v]);
    }
    __syncthreads();
  }
  // Yt = x_tile - acc; load R_PP (upper)
#pragma unroll
  for (int u = 0; u < 4; ++u)
#pragma unroll
    for (int v = 0; v < 4; ++v)
      Yt[ty * 4 + u][tx * 4 + v] =
          xb[(size_t)(n0 + ty * 4 + u) * DIN + j0 + tx * 4 + v] - acc[u][v];
  for (int idx = t; idx < 4096; idx += 256) {
    int i2 = idx >> 6, c2 = idx & 63;
    Rp[i2][c2] = (c2 >= i2) ? R[(size_t)(j0 + i2) * DIN + j0 + c2] : 0.0f;
  }
  __syncthreads();
  if (t < 64) {
    float v[64];
#pragma unroll
    for (int i = 0; i < 64; ++i) v[i] = Yt[t][i];
#pragma unroll
    for (int i = 63; i >= 0; --i) {
      float val = v[i];
      for (int j = i + 1; j < 64; ++j) val -= Rp[i][j] * v[j];
      v[i] = val / Rp[i][i];
    }
#pragma unroll
    for (int i = 0; i < 64; ++i) Yt[t][i] = v[i];
  }
  __syncthreads();
  for (int idx = t; idx < 4096; idx += 256) {
    int nn = idx >> 6, cc = idx & 63;
    yb[(size_t)(n0 + nn) * DIN + j0 + cc] = Yt[nn][cc];
  }
}

// ---------------- K10: yE_b = y_b @ E  (batched NN 256x384x512) ----------------
__global__ __launch_bounds__(256) void k_yE(const float* __restrict__ y, const float* __restrict__ E,
                                            float* __restrict__ yE) {
  int b = blockIdx.z;
  int n0 = blockIdx.x * 64, j0 = blockIdx.y * 64;
  const float* yb = y + (size_t)b * N_ * DIN;
  float* yEb = yE + (size_t)b * N_ * P2;
  __shared__ float As[16][65], Bs[16][66];
  int t = threadIdx.x;
  int tx = t & 15, ty = t >> 4;
  float acc[4][4] = {};
  for (int k0 = 0; k0 < DIN; k0 += 16) {
    for (int idx = t; idx < 1024; idx += 256) {
      int nn = idx >> 4, kk = idx & 15;
      As[kk][nn] = yb[(size_t)(n0 + nn) * DIN + k0 + kk];
    }
    for (int idx = t; idx < 1024; idx += 256) {
      int kk = idx >> 6, jj = idx & 63;
      Bs[kk][jj] = E[(size_t)(k0 + kk) * P2 + j0 + jj];
    }
    __syncthreads();
#pragma unroll
    for (int kk = 0; kk < 16; ++kk) {
      float a[4], bv[4];
#pragma unroll
      for (int u = 0; u < 4; ++u) a[u] = As[kk][ty * 4 + u];
#pragma unroll
      for (int v = 0; v < 4; ++v) bv[v] = Bs[kk][tx * 4 + v];
#pragma unroll
      for (int u = 0; u < 4; ++u)
#pragma unroll
        for (int v = 0; v < 4; ++v) acc[u][v] = fmaf(a[u], bv[v], acc[u][v]);
    }
    __syncthreads();
  }
#pragma unroll
  for (int u = 0; u < 4; ++u)
#pragma unroll
    for (int v = 0; v < 4; ++v)
      yEb[(size_t)(n0 + ty * 4 + u) * P2 + j0 + tx * 4 + v] = acc[u][v];
}

// ---------------- K11: build u (in-place in yE, halves swapped+scaled) and v ----------------
__global__ void k_uv(const float* __restrict__ cp, const float* __restrict__ gate,
                     float* __restrict__ yE, float* __restrict__ v) {
  int idx = blockIdx.x * 256 + threadIdx.x;
  if (idx >= B_ * N_ * P1) return;
  int q = idx % P1;
  int bn = idx / P1;
  int b = bn / N_;
  int k = q / RANK_;
  float cc = cp[b * K_ + k];
  size_t base = (size_t)bn * P2;
  float yR = yE[base + q];
  float yP = yE[base + P1 + q];
  yE[base + q] = 0.5f * cc * yP;       // u1 (pairs Rcat^T)
  yE[base + P1 + q] = 0.5f * cc * yR;  // u2 (pairs Pcat^T)
  v[(size_t)bn * P1 + q] = gate[b] * cc * yR;
}

// ---------------- K12: w = gate*(y - x - u@E^T)  (batched NT, in-place into y) ----------------
__global__ __launch_bounds__(256) void k_w(const float* __restrict__ u, const float* __restrict__ E,
                                           const float* __restrict__ x, const float* __restrict__ gate,
                                           float* __restrict__ yio) {
  int b = blockIdx.z;
  int n0 = blockIdx.x * 64, d0 = blockIdx.y * 64;
  const float* ub = u + (size_t)b * N_ * P2;
  __shared__ float As[16][65], Bs[16][65];
  int t = threadIdx.x;
  int tx = t & 15, ty = t >> 4;
  float acc[4][4] = {};
  for (int q0 = 0; q0 < P2; q0 += 16) {
    for (int idx = t; idx < 1024; idx += 256) {
      int nn = idx >> 4, qq = idx & 15;
      As[qq][nn] = ub[(size_t)(n0 + nn) * P2 + q0 + qq];
    }
    for (int idx = t; idx < 1024; idx += 256) {
      int dd = idx >> 4, qq = idx & 15;
      Bs[qq][dd] = E[(size_t)(d0 + dd) * P2 + q0 + qq];
    }
    __syncthreads();
#pragma unroll
    for (int qq = 0; qq < 16; ++qq) {
      float a[4], bv[4];
#pragma unroll
      for (int u2 = 0; u2 < 4; ++u2) a[u2] = As[qq][ty * 4 + u2];
#pragma unroll
      for (int v2 = 0; v2 < 4; ++v2) bv[v2] = Bs[qq][tx * 4 + v2];
#pragma unroll
      for (int u2 = 0; u2 < 4; ++u2)
#pragma unroll
        for (int v2 = 0; v2 < 4; ++v2) acc[u2][v2] = fmaf(a[u2], bv[v2], acc[u2][v2]);
    }
    __syncthreads();
  }
  float gt = gate[b];
#pragma unroll
  for (int u2 = 0; u2 < 4; ++u2)
#pragma unroll
    for (int v2 = 0; v2 < 4; ++v2) {
      size_t gi = ((size_t)b * N_ + n0 + ty * 4 + u2) * DIN + d0 + tx * 4 + v2;
      yio[gi] = gt * (yio[gi] - x[gi] - acc[u2][v2]);
    }
}

// ---------------- K13: fused output GEMM: out = [x|w|v] @ [W;U0;Lcat]^T + bias ----------------
__global__ __launch_bounds__(256) void k_final(const float* __restrict__ x, const float* __restrict__ wbuf,
                                               const float* __restrict__ vbuf, const float* __restrict__ Wsh,
                                               const float* __restrict__ U0, const float* __restrict__ Lcat,
                                               const float* __restrict__ bias, float* __restrict__ out) {
  __shared__ __align__(16) float As[16][132];
  __shared__ __align__(16) float Bs[16][132];
  int c0 = blockIdx.x * 128;
  int r0 = blockIdx.y * 128;
  int t = threadIdx.x;
  int tx = t & 15, ty = t >> 4;
  int lrow = t >> 1, lk8 = (t & 1) << 3;
  float acc[8][8] = {};
  for (int k0 = 0; k0 < 1216; k0 += 16) {
    const float* Aseg; const float* Bseg; int ksz, kloc;
    if (k0 < 512)        { Aseg = x;    Bseg = Wsh;  ksz = 512; kloc = k0; }
    else if (k0 < 1024)  { Aseg = wbuf; Bseg = U0;   ksz = 512; kloc = k0 - 512; }
    else                 { Aseg = vbuf; Bseg = Lcat; ksz = 192; kloc = k0 - 1024; }
    const float* pa = Aseg + (size_t)(r0 + lrow) * ksz + kloc + lk8;
    const float* pb = Bseg + (size_t)(c0 + lrow) * ksz + kloc + lk8;
    float4 a0 = *(const float4*)pa;
    float4 a1 = *(const float4*)(pa + 4);
    float4 b0 = *(const float4*)pb;
    float4 b1 = *(const float4*)(pb + 4);
    __syncthreads();
    As[lk8 + 0][lrow] = a0.x; As[lk8 + 1][lrow] = a0.y; As[lk8 + 2][lrow] = a0.z; As[lk8 + 3][lrow] = a0.w;
    As[lk8 + 4][lrow] = a1.x; As[lk8 + 5][lrow] = a1.y; As[lk8 + 6][lrow] = a1.z; As[lk8 + 7][lrow] = a1.w;
    Bs[lk8 + 0][lrow] = b0.x; Bs[lk8 + 1][lrow] = b0.y; Bs[lk8 + 2][lrow] = b0.z; Bs[lk8 + 3][lrow] = b0.w;
    Bs[lk8 + 4][lrow] = b1.x; Bs[lk8 + 5][lrow] = b1.y; Bs[lk8 + 6][lrow] = b1.z; Bs[lk8 + 7][lrow] = b1.w;
    __syncthreads();
#pragma unroll
    for (int kk = 0; kk < 16; ++kk) {
      float4 av0 = *(const float4*)&As[kk][ty * 8];
      float4 av1 = *(const float4*)&As[kk][ty * 8 + 4];
      float4 bv0 = *(const float4*)&Bs[kk][tx * 8];
      float4 bv1 = *(const float4*)&Bs[kk][tx * 8 + 4];
      float aa[8] = {av0.x, av0.y, av0.z, av0.w, av1.x, av1.y, av1.z, av1.w};
      float bb[8] = {bv0.x, bv0.y, bv0.z, bv0.w, bv1.x, bv1.y, bv1.z, bv1.w};
#pragma unroll
      for (int u2 = 0; u2 < 8; ++u2)
#pragma unroll
        for (int v2 = 0; v2 < 8; ++v2) acc[u2][v2] = fmaf(aa[u2], bb[v2], acc[u2][v2]);
    }
  }
#pragma unroll
  for (int u2 = 0; u2 < 8; ++u2) {
    size_t ro = (size_t)(r0 + ty * 8 + u2) * DOUT + c0 + tx * 8;
#pragma unroll
    for (int v2 = 0; v2 < 8; ++v2) out[ro + v2] = acc[u2][v2] + bias[c0 + tx * 8 + v2];
  }
}

extern "C" void kernel_launch(void* const* d_in, const int* in_sizes, int n_in,
                              void* d_out, int out_size, void* d_ws, size_t ws_size,
                              hipStream_t stream) {
  (void)in_sizes; (void)n_in; (void)out_size; (void)ws_size;
  const float* x     = (const float*)d_in[0];
  const float* Wsh   = (const float*)d_in[1];
  const float* bias  = (const float*)d_in[2];
  const float* U0    = (const float*)d_in[3];
  const float* leftb = (const float*)d_in[4];
  const float* rightb= (const float*)d_in[5];
  const float* W1    = (const float*)d_in[6];
  const float* b1    = (const float*)d_in[7];
  const float* Wc    = (const float*)d_in[8];
  const float* bc    = (const float*)d_in[9];
  const float* Wg    = (const float*)d_in[10];
  const float* bg    = (const float*)d_in[11];
  float* out = (float*)d_out;

  float* wsf = (float*)d_ws;
  size_t o = 0;
  float* z     = wsf + o; o += B_ * CD;          // 49152
  float* coeff = wsf + o; o += B_ * K_;          // 512
  float* gate  = wsf + o; o += 64;
  float* norms = wsf + o; o += 64;
  float* cp    = wsf + o; o += B_ * K_;
  float* Lcat  = wsf + o; o += (size_t)DOUT * P1; // 393216
  float* E     = wsf + o; o += (size_t)DIN * P2;  // 196608
  float* GLL   = wsf + o; o += P1 * P1;           // 36864
  float* GE    = wsf + o; o += P2 * P2;           // 147456
  float* M0    = wsf + o; o += P2 * P2;           // 147456
  float* v     = wsf + o; o += (size_t)B_ * N_ * P1;  // 1572864
  float* y     = wsf + o; o += (size_t)B_ * N_ * DIN; // 4194304
  float* yE    = wsf + o; o += (size_t)B_ * N_ * P2;  // 3145728
  // H (B*512*384 = 6291456 floats) aliases [y, y+y_len+yE_len): dead before y is written
  float* H = y;
  // G (32 x 512 x 512 = 8388608 floats = 33.5MB) lives in d_out; fully overwritten by k_final
  float* G = out;

  k_stats<<<B_, DIN, 0, stream>>>(x, z);
  k_controller<<<B_, HC, 0, stream>>>(z, W1, b1, Wc, bc, Wg, bg, coeff, gate);
  k_copy_bases<<<(DOUT * P1 + DIN * P1 + 255) / 256, 256, 0, stream>>>(leftb, rightb, Lcat, E);
  // Pcat = U0^T Lcat -> E[:,192:384]
  k_gemm_tn<<<dim3(DIN / 32, P1 / 32), 256, 0, stream>>>(U0, Lcat, E + P1, DIN, P1, DOUT, DIN, P1, P2);
  // GLL = Lcat^T Lcat
  k_gemm_tn<<<dim3(P1 / 32, P1 / 32), 256, 0, stream>>>(Lcat, Lcat, GLL, P1, P1, DOUT, P1, P1, P1);
  // GE = E^T E  (blocks: GRR, GRP; GPR, GPP)
  k_gemm_tn<<<dim3(P2 / 32, P2 / 32), 256, 0, stream>>>(E, E, GE, P2, P2, DIN, P2, P2, P2);
  k_norms<<<K_, 64, 0, stream>>>(GLL, GE, norms);
  k_cprime<<<1, 512, 0, stream>>>(coeff, norms, cp);
  k_m0<<<(P2 * P2 + 255) / 256, 256, 0, stream>>>(GLL, GE, M0);
  k_H<<<dim3(DIN / 64, P2 / 64, B_), 256, 0, stream>>>(E, M0, cp, H);
  k_G<<<dim3(DIN / 64, DIN / 64, B_), 256, 0, stream>>>(H, E, cp, G);
  // blocked Cholesky: 8 panels of width 64
  for (int p = 0; p < 8; ++p) {
    int j0 = p * 64;
    int nt = 7 - p;
    k_chol_dp<<<dim3(nt + 1, B_), 64, 0, stream>>>(G, j0);
    if (nt > 0)
      k_chol_tr<<<dim3(nt * (nt + 1) / 2, B_), 256, 0, stream>>>(G, j0, nt);
  }
  // blocked trisolve: panels backward
  for (int p = 7; p >= 0; --p)
    k_tri<<<dim3(N_ / 64, B_), 256, 0, stream>>>(x, G, y, p * 64);
  k_yE<<<dim3(N_ / 64, P2 / 64, B_), 256, 0, stream>>>(y, E, yE);
  k_uv<<<(B_ * N_ * P1 + 255) / 256, 256, 0, stream>>>(cp, gate, yE, v);
  k_w<<<dim3(N_ / 64, DIN / 64, B_), 256, 0, stream>>>(yE, E, x, gate, y);
  k_final<<<dim3(DOUT / 128, (B_ * N_) / 128), 256, 0, stream>>>(x, y, v, Wsh, U0, Lcat, bias, out);
}

// Round 3
// 2112.530 us; speedup vs baseline: 1.6990x; 1.2182x over previous
//
#include <hip/hip_runtime.h>
#include <math.h>

#define B_    32
#define N_    256
#define DIN   512
#define DOUT  2048
#define RANK_ 12
#define K_    16
#define HC    192
#define CD    1536
#define P1    192
#define P2    384

typedef short short8 __attribute__((ext_vector_type(8)));
typedef float f32x4 __attribute__((ext_vector_type(4)));

__device__ inline short bf16r(float f) {
  unsigned u = __float_as_uint(f);
  unsigned r = (u + 0x7FFFu + ((u >> 16) & 1u)) >> 16;
  return (short)r;
}

// ---------------- K1: z = [cls, mean, var] ----------------
__global__ void k_stats(const float* __restrict__ x, float* __restrict__ z) {
  int b = blockIdx.x, d = threadIdx.x;
  const float* xb = x + (size_t)b * N_ * DIN;
  float s = 0.f, s2 = 0.f;
  for (int n = 0; n < N_; ++n) {
    float t = xb[(size_t)n * DIN + d];
    s += t; s2 += t * t;
  }
  float mean = s * (1.0f / N_);
  float var = s2 * (1.0f / N_) - mean * mean;
  float* zb = z + (size_t)b * CD;
  zb[d] = xb[d];
  zb[DIN + d] = mean;
  zb[2 * DIN + d] = var;
}

// ---------------- K2: controller ----------------
__global__ void k_controller(const float* __restrict__ z, const float* __restrict__ W1,
                             const float* __restrict__ b1, const float* __restrict__ Wc,
                             const float* __restrict__ bc, const float* __restrict__ Wg,
                             const float* __restrict__ bg, float* __restrict__ coeff,
                             float* __restrict__ gate) {
  int b = blockIdx.x, j = threadIdx.x;
  __shared__ float zs[CD];
  __shared__ float hs[HC];
  const float* zb = z + (size_t)b * CD;
  for (int i = j; i < CD; i += HC) zs[i] = zb[i];
  __syncthreads();
  float acc = b1[j];
  for (int d = 0; d < CD; ++d) acc = fmaf(zs[d], W1[(size_t)d * HC + j], acc);
  float x3 = acc * acc * acc;
  float hj = 0.5f * acc * (1.0f + tanhf(0.7978845608028654f * (acc + 0.044715f * x3)));
  hs[j] = hj;
  __syncthreads();
  if (j < K_) {
    float c = bc[j];
    for (int t = 0; t < HC; ++t) c = fmaf(hs[t], Wc[t * K_ + j], c);
    coeff[b * K_ + j] = c;
  } else if (j == K_) {
    float g = bg[0];
    for (int t = 0; t < HC; ++t) g = fmaf(hs[t], Wg[t], g);
    gate[b] = 1.0f / (1.0f + expf(-g));
  }
}

// ---------------- K3: repack bases: Lcat (2048x192), E[:,0:192]=Rcat ----------------
__global__ void k_copy_bases(const float* __restrict__ leftb, const float* __restrict__ rightb,
                             float* __restrict__ Lcat, float* __restrict__ E) {
  int idx = blockIdx.x * 256 + threadIdx.x;
  const int totL = DOUT * P1;
  const int totR = DIN * P1;
  if (idx < totL) {
    int m = idx / P1, j = idx - m * P1;
    int k = j / RANK_, r = j - k * RANK_;
    Lcat[idx] = leftb[((size_t)k * DOUT + m) * RANK_ + r];
  } else if (idx < totL + totR) {
    int i2 = idx - totL;
    int d = i2 / P1, j = i2 - d * P1;
    int k = j / RANK_, r = j - k * RANK_;
    E[(size_t)d * P2 + j] = rightb[((size_t)k * DIN + d) * RANK_ + r];
  }
}

// ---------------- pack B: Bcat[n][0:512|512:1024|1024:1216] = bf16(Wsh|U0|Lcat) ----------------
__global__ void k_pack_B(const float* __restrict__ Wsh, const float* __restrict__ U0,
                         const float* __restrict__ LcatF, short* __restrict__ Bcat) {
  int idx = blockIdx.x * 256 + threadIdx.x;  // 8-elem groups: 2048*152
  if (idx >= DOUT * 152) return;
  int row = idx / 152, g = idx - row * 152;
  const float* src;
  if (g < 64)       src = Wsh + (size_t)row * DIN + g * 8;
  else if (g < 128) src = U0 + (size_t)row * DIN + (g - 64) * 8;
  else              src = LcatF + (size_t)row * P1 + (g - 128) * 8;
  short8 o;
#pragma unroll
  for (int e = 0; e < 8; ++e) o[e] = bf16r(src[e]);
  *(short8*)(Bcat + (size_t)row * 1216 + g * 8) = o;
}

// ---------------- pack x -> bf16 (into dead y region) ----------------
__global__ void k_pack_x(const float* __restrict__ x, short* __restrict__ xb) {
  int i = blockIdx.x * 256 + threadIdx.x;  // 8-elem groups: 8192*512/8
  const float* s = x + (size_t)i * 8;
  short8 o;
#pragma unroll
  for (int e = 0; e < 8; ++e) o[e] = bf16r(s[e]);
  *(short8*)(xb + (size_t)i * 8) = o;
}

// ---------------- generic TN GEMM: C[i,j] = sum_k A[k*lda+i]*B[k*ldb+j] ----------------
__global__ __launch_bounds__(256) void k_gemm_tn(const float* __restrict__ A,
                                                 const float* __restrict__ B,
                                                 float* __restrict__ C,
                                                 int M, int N, int Kd, int lda, int ldb, int ldc) {
  __shared__ float As[32][33], Bs[32][33];
  int i0 = blockIdx.x * 32, j0 = blockIdx.y * 32;
  int t = threadIdx.x;
  int ii = t & 31, j4 = (t >> 5) * 4;
  float acc[4] = {0.f, 0.f, 0.f, 0.f};
  for (int kb = 0; kb < Kd; kb += 32) {
    for (int idx = t; idx < 1024; idx += 256) {
      int kk = idx >> 5, c = idx & 31;
      As[kk][c] = A[(size_t)(kb + kk) * lda + i0 + c];
      Bs[kk][c] = B[(size_t)(kb + kk) * ldb + j0 + c];
    }
    __syncthreads();
#pragma unroll 8
    for (int kk = 0; kk < 32; ++kk) {
      float a = As[kk][ii];
#pragma unroll
      for (int q = 0; q < 4; ++q) acc[q] = fmaf(a, Bs[kk][j4 + q], acc[q]);
    }
    __syncthreads();
  }
#pragma unroll
  for (int q = 0; q < 4; ++q) C[(size_t)(i0 + ii) * ldc + j0 + j4 + q] = acc[q];
}

// ---------------- K4b: per-k tangent norms from Gram blocks ----------------
__global__ void k_norms(const float* __restrict__ GLL, const float* __restrict__ GE,
                        float* __restrict__ norms) {
  int k = blockIdx.x, t = threadIdx.x;
  float s1 = 0.f, s2 = 0.f, s3 = 0.f;
  for (int idx = t; idx < RANK_ * RANK_; idx += 64) {
    int r = idx / RANK_, s = idx - r * RANK_;
    int p = k * RANK_ + r, q = k * RANK_ + s;
    float gll = GLL[p * P1 + q];
    float grr = GE[p * P2 + q];
    float gpp = GE[(P1 + p) * P2 + (P1 + q)];
    float gpr = GE[(P1 + p) * P2 + q];
    float gprt = GE[(P1 + q) * P2 + p];
    s1 += gll * grr;
    s2 += gpp * grr;
    s3 += gpr * gprt;
  }
#pragma unroll
  for (int off = 32; off > 0; off >>= 1) {
    s1 += __shfl_down(s1, off);
    s2 += __shfl_down(s2, off);
    s3 += __shfl_down(s3, off);
  }
  if (t == 0) norms[k] = sqrtf(fmaxf(s1 - 0.5f * (s2 + s3), 0.0f));
}

// ---------------- K5: c' = coeff / max(norm,1e-6) ----------------
__global__ void k_cprime(const float* __restrict__ coeff, const float* __restrict__ norms,
                         float* __restrict__ cp) {
  int t = threadIdx.x;
  if (t < B_ * K_) {
    int k = t & 15;
    cp[t] = coeff[t] / fmaxf(norms[k], 1e-6f);
  }
}

// ---------------- K5b: assemble M0 (384x384) ----------------
__global__ void k_m0(const float* __restrict__ GLL, const float* __restrict__ GE,
                     float* __restrict__ M0) {
  int idx = blockIdx.x * 256 + threadIdx.x;
  if (idx >= P2 * P2) return;
  int p = idx / P2, q = idx - p * P2;
  float v;
  if (p < P1) {
    if (q < P1) v = GLL[p * P1 + q] - 0.75f * GE[(P1 + p) * P2 + (P1 + q)];
    else        v = -0.25f * GE[(P1 + p) * P2 + (q - P1)];
  } else {
    if (q < P1) v = -0.25f * GE[(P1 + q) * P2 + (p - P1)];
    else        v = 0.25f * GE[(p - P1) * P2 + (q - P1)];
  }
  M0[idx] = v;
}

// ---------------- K6: H_b = (E .* chat_b) @ M0   (batched 512x384x384) ----------------
__global__ __launch_bounds__(256) void k_H(const float* __restrict__ E, const float* __restrict__ M0,
                                           const float* __restrict__ cp, float* __restrict__ H) {
  int b = blockIdx.z;
  int i0 = blockIdx.x * 64, q0 = blockIdx.y * 64;
  int t = threadIdx.x;
  __shared__ float As[16][65], Bs[16][66];
  const float* cpb = cp + b * K_;
  float* Hb = H + (size_t)b * DIN * P2;
  int tx = t & 15, ty = t >> 4;
  float acc[4][4] = {};
  for (int p0 = 0; p0 < P2; p0 += 16) {
    for (int idx = t; idx < 1024; idx += 256) {
      int ii = idx >> 4, pp = idx & 15;
      int p = p0 + pp;
      int pk = (p >= P1 ? p - P1 : p) / RANK_;
      As[pp][ii] = E[(size_t)(i0 + ii) * P2 + p] * cpb[pk];
    }
    for (int idx = t; idx < 1024; idx += 256) {
      int pp = idx >> 6, qq = idx & 63;
      Bs[pp][qq] = M0[(size_t)(p0 + pp) * P2 + q0 + qq];
    }
    __syncthreads();
#pragma unroll
    for (int pp = 0; pp < 16; ++pp) {
      float a[4], bv[4];
#pragma unroll
      for (int u = 0; u < 4; ++u) a[u] = As[pp][ty * 4 + u];
#pragma unroll
      for (int u = 0; u < 4; ++u) bv[u] = Bs[pp][tx * 4 + u];
#pragma unroll
      for (int u = 0; u < 4; ++u)
#pragma unroll
        for (int v = 0; v < 4; ++v) acc[u][v] = fmaf(a[u], bv[v], acc[u][v]);
    }
    __syncthreads();
  }
#pragma unroll
  for (int u = 0; u < 4; ++u)
#pragma unroll
    for (int v = 0; v < 4; ++v)
      Hb[(size_t)(i0 + ty * 4 + u) * P2 + q0 + tx * 4 + v] = acc[u][v];
}

// ---------------- K7: G_b = I + H_b @ (E .* chat_b)^T ----------------
__global__ __launch_bounds__(256) void k_G(const float* __restrict__ H, const float* __restrict__ E,
                                           const float* __restrict__ cp, float* __restrict__ G) {
  int b = blockIdx.z;
  int i0 = blockIdx.x * 64, j0 = blockIdx.y * 64;
  int t = threadIdx.x;
  __shared__ float As[16][65], Bs[16][65];
  const float* cpb = cp + b * K_;
  const float* Hb = H + (size_t)b * DIN * P2;
  float* Gb = G + (size_t)b * DIN * DIN;
  int tx = t & 15, ty = t >> 4;
  float acc[4][4] = {};
  for (int q0 = 0; q0 < P2; q0 += 16) {
    for (int idx = t; idx < 1024; idx += 256) {
      int ii = idx >> 4, qq = idx & 15;
      As[qq][ii] = Hb[(size_t)(i0 + ii) * P2 + q0 + qq];
    }
    for (int idx = t; idx < 1024; idx += 256) {
      int jj = idx >> 4, qq = idx & 15;
      int q = q0 + qq;
      int pk = (q >= P1 ? q - P1 : q) / RANK_;
      Bs[qq][jj] = E[(size_t)(j0 + jj) * P2 + q] * cpb[pk];
    }
    __syncthreads();
#pragma unroll
    for (int qq = 0; qq < 16; ++qq) {
      float a[4], bv[4];
#pragma unroll
      for (int u = 0; u < 4; ++u) a[u] = As[qq][ty * 4 + u];
#pragma unroll
      for (int u = 0; u < 4; ++u) bv[u] = Bs[qq][tx * 4 + u];
#pragma unroll
      for (int u = 0; u < 4; ++u)
#pragma unroll
        for (int v = 0; v < 4; ++v) acc[u][v] = fmaf(a[u], bv[v], acc[u][v]);
    }
    __syncthreads();
  }
#pragma unroll
  for (int u = 0; u < 4; ++u)
#pragma unroll
    for (int v = 0; v < 4; ++v) {
      int gi = i0 + ty * 4 + u, gj = j0 + tx * 4 + v;
      Gb[(size_t)gi * DIN + gj] = acc[u][v] + (gi == gj ? 1.0f : 0.0f);
    }
}

// ---------------- K8a: panel step — redundant 64x64 diag factor + panel solve ----------------
__global__ __launch_bounds__(64) void k_chol_dp(float* __restrict__ G, int j0) {
  int b = blockIdx.y;
  int role = blockIdx.x;
  float* Gb = G + (size_t)b * DIN * DIN;
  __shared__ float D[64][65];
  __shared__ float dinv[64];
  int t = threadIdx.x;
#pragma unroll 8
  for (int i = 0; i < 64; ++i) D[i][t] = Gb[(size_t)(j0 + i) * DIN + j0 + t];
  __syncthreads();
  for (int j = 0; j < 64; ++j) {
    if (t == j) D[j][j] = sqrtf(fmaxf(D[j][j], 1e-30f));
    __syncthreads();
    float djj = D[j][j];
    if (t > j) D[j][t] /= djj;
    __syncthreads();
    if (t > j) {
      float djt = D[j][t];
      for (int i = j + 1; i <= t; ++i) D[i][t] -= D[j][i] * djt;
    }
    __syncthreads();
  }
  dinv[t] = 1.0f / D[t][t];
  __syncthreads();
  if (role == 0) {
#pragma unroll 8
    for (int i = 0; i < 64; ++i)
      if (t >= i) Gb[(size_t)(j0 + i) * DIN + j0 + t] = D[i][t];
  } else {
    int c = j0 + 64 + (role - 1) * 64 + t;
    float a[64];
#pragma unroll
    for (int i = 0; i < 64; ++i) a[i] = Gb[(size_t)(j0 + i) * DIN + c];
#pragma unroll
    for (int jj = 0; jj < 64; ++jj) {
      float val = a[jj];
      for (int tt = 0; tt < jj; ++tt) val -= D[tt][jj] * a[tt];
      a[jj] = val * dinv[jj];
    }
#pragma unroll
    for (int i = 0; i < 64; ++i) Gb[(size_t)(j0 + i) * DIN + c] = a[i];
  }
}

// ---------------- K8b: trailing update C -= P^T P over 64x64 tile pairs ----------------
__global__ __launch_bounds__(256) void k_chol_tr(float* __restrict__ G, int j0, int nt) {
  int b = blockIdx.y;
  int pi = blockIdx.x;
  int ti = 0, accum = 0;
  while (pi >= accum + (nt - ti)) { accum += nt - ti; ++ti; }
  int tc = ti + (pi - accum);
  float* Gb = G + (size_t)b * DIN * DIN;
  __shared__ float As[64][65], Bs[64][65];
  int t = threadIdx.x;
  int ibase = j0 + 64 + ti * 64, cbase = j0 + 64 + tc * 64;
  for (int idx = t; idx < 4096; idx += 256) {
    int j = idx >> 6, c = idx & 63;
    As[j][c] = Gb[(size_t)(j0 + j) * DIN + ibase + c];
    Bs[j][c] = Gb[(size_t)(j0 + j) * DIN + cbase + c];
  }
  __syncthreads();
  int tx = t & 15, ty = t >> 4;
  float acc[4][4] = {};
#pragma unroll 8
  for (int k = 0; k < 64; ++k) {
    float a[4], bv[4];
#pragma unroll
    for (int u = 0; u < 4; ++u) a[u] = As[k][ty * 4 + u];
#pragma unroll
    for (int v = 0; v < 4; ++v) bv[v] = Bs[k][tx * 4 + v];
#pragma unroll
    for (int u = 0; u < 4; ++u)
#pragma unroll
      for (int v = 0; v < 4; ++v) acc[u][v] = fmaf(a[u], bv[v], acc[u][v]);
  }
#pragma unroll
  for (int u = 0; u < 4; ++u) {
    size_t ro = (size_t)(ibase + ty * 4 + u) * DIN + cbase + tx * 4;
#pragma unroll
    for (int v = 0; v < 4; ++v) Gb[ro + v] -= acc[u][v];
  }
}

// ---------------- K8c: Wd[b][p] = inv(R_PP) for all 8 diag blocks ----------------
// grid (8, B_), 64 threads; lane c owns column c (no cross-lane deps after load).
__global__ __launch_bounds__(64) void k_tinv_diag(const float* __restrict__ G, float* __restrict__ Wd) {
  int p = blockIdx.x, b = blockIdx.y;
  const float* R = G + (size_t)b * DIN * DIN;
  int j0 = p * 64;
  __shared__ float Rls[64][65];
  __shared__ float Wls[64][65];
  int c = threadIdx.x;
#pragma unroll 4
  for (int i = 0; i < 64; ++i) Rls[i][c] = R[(size_t)(j0 + i) * DIN + j0 + c];
#pragma unroll 4
  for (int i = 0; i < 64; ++i) Wls[i][c] = 0.0f;
  __syncthreads();
  Wls[c][c] = 1.0f / Rls[c][c];
  for (int i = 62; i >= 0; --i) {
    float s = 0.0f;
    for (int j = i + 1; j < 64; ++j) s = fmaf(Rls[i][j], Wls[j][c], s);
    if (c > i) Wls[i][c] = -s / Rls[i][i];
  }
  float* Wp = Wd + ((size_t)b * 8 + p) * 4096;
#pragma unroll 4
  for (int i = 0; i < 64; ++i) Wp[i * 64 + c] = Wls[i][c];
}

// ---------------- K9: trisolve panel as pure GEMM: y[:,P] = (x[:,P] - y[:,>P] R[P,>P]^T) Wd^T ----
__global__ __launch_bounds__(256) void k_tri2(const float* __restrict__ x, const float* __restrict__ G,
                                              const float* __restrict__ Wd, float* __restrict__ y,
                                              int j0) {
  int b = blockIdx.y;
  int n0 = blockIdx.x * 64;
  const float* R = G + (size_t)b * DIN * DIN;
  const float* xb2 = x + (size_t)b * N_ * DIN;
  float* yb = y + (size_t)b * N_ * DIN;
  __shared__ float As[16][65], Bs[16][65];
  __shared__ float Yt[64][65];
  __shared__ float Ws[64][65];
  int t = threadIdx.x;
  int tx = t & 15, ty = t >> 4;
  float acc[4][4] = {};
  for (int k0 = j0 + 64; k0 < DIN; k0 += 16) {
    for (int idx = t; idx < 1024; idx += 256) {
      int nn = idx >> 4, kk = idx & 15;
      As[kk][nn] = yb[(size_t)(n0 + nn) * DIN + k0 + kk];
      Bs[kk][nn] = R[(size_t)(j0 + nn) * DIN + k0 + kk];
    }
    __syncthreads();
#pragma unroll
    for (int kk = 0; kk < 16; ++kk) {
      float a[4], bv[4];
#pragma unroll
      for (int u = 0; u < 4; ++u) a[u] = As[kk][ty * 4 + u];
#pragma unroll
      for (int v = 0; v < 4; ++v) bv[v] = Bs[kk][tx * 4 + v];
#pragma unroll
      for (int u = 0; u < 4; ++u)
#pragma unroll
        for (int v = 0; v < 4; ++v) acc[u][v] = fmaf(a[u], bv[v], acc[u][v]);
    }
    __syncthreads();
  }
#pragma unroll
  for (int u = 0; u < 4; ++u)
#pragma unroll
    for (int v = 0; v < 4; ++v)
      Yt[ty * 4 + u][tx * 4 + v] =
          xb2[(size_t)(n0 + ty * 4 + u) * DIN + j0 + tx * 4 + v] - acc[u][v];
  const float* Wp = Wd + ((size_t)b * 8 + (j0 >> 6)) * 4096;
  for (int idx = t; idx < 4096; idx += 256) {
    Ws[idx >> 6][idx & 63] = Wp[idx];
  }
  __syncthreads();
  float a2[4][4] = {};
#pragma unroll 8
  for (int jj = 0; jj < 64; ++jj) {
    float aa[4], bb[4];
#pragma unroll
    for (int u = 0; u < 4; ++u) aa[u] = Yt[ty * 4 + u][jj];
#pragma unroll
    for (int v = 0; v < 4; ++v) bb[v] = Ws[tx * 4 + v][jj];
#pragma unroll
    for (int u = 0; u < 4; ++u)
#pragma unroll
      for (int v = 0; v < 4; ++v) a2[u][v] = fmaf(aa[u], bb[v], a2[u][v]);
  }
#pragma unroll
  for (int u = 0; u < 4; ++u)
#pragma unroll
    for (int v = 0; v < 4; ++v)
      yb[(size_t)(n0 + ty * 4 + u) * DIN + j0 + tx * 4 + v] = a2[u][v];
}

// ---------------- K10: yE_b = y_b @ E ----------------
__global__ __launch_bounds__(256) void k_yE(const float* __restrict__ y, const float* __restrict__ E,
                                            float* __restrict__ yE) {
  int b = blockIdx.z;
  int n0 = blockIdx.x * 64, j0 = blockIdx.y * 64;
  const float* yb = y + (size_t)b * N_ * DIN;
  float* yEb = yE + (size_t)b * N_ * P2;
  __shared__ float As[16][65], Bs[16][66];
  int t = threadIdx.x;
  int tx = t & 15, ty = t >> 4;
  float acc[4][4] = {};
  for (int k0 = 0; k0 < DIN; k0 += 16) {
    for (int idx = t; idx < 1024; idx += 256) {
      int nn = idx >> 4, kk = idx & 15;
      As[kk][nn] = yb[(size_t)(n0 + nn) * DIN + k0 + kk];
    }
    for (int idx = t; idx < 1024; idx += 256) {
      int kk = idx >> 6, jj = idx & 63;
      Bs[kk][jj] = E[(size_t)(k0 + kk) * P2 + j0 + jj];
    }
    __syncthreads();
#pragma unroll
    for (int kk = 0; kk < 16; ++kk) {
      float a[4], bv[4];
#pragma unroll
      for (int u = 0; u < 4; ++u) a[u] = As[kk][ty * 4 + u];
#pragma unroll
      for (int v = 0; v < 4; ++v) bv[v] = Bs[kk][tx * 4 + v];
#pragma unroll
      for (int u = 0; u < 4; ++u)
#pragma unroll
        for (int v = 0; v < 4; ++v) acc[u][v] = fmaf(a[u], bv[v], acc[u][v]);
    }
    __syncthreads();
  }
#pragma unroll
  for (int u = 0; u < 4; ++u)
#pragma unroll
    for (int v = 0; v < 4; ++v)
      yEb[(size_t)(n0 + ty * 4 + u) * P2 + j0 + tx * 4 + v] = acc[u][v];
}

// ---------------- K11: build u (in-place in yE) and vb (bf16) ----------------
__global__ void k_uv(const float* __restrict__ cp, const float* __restrict__ gate,
                     float* __restrict__ yE, short* __restrict__ vb) {
  int idx = blockIdx.x * 256 + threadIdx.x;
  if (idx >= B_ * N_ * P1) return;
  int q = idx % P1;
  int bn = idx / P1;
  int b = bn / N_;
  int k = q / RANK_;
  float cc = cp[b * K_ + k];
  size_t base = (size_t)bn * P2;
  float yR = yE[base + q];
  float yP = yE[base + P1 + q];
  yE[base + q] = 0.5f * cc * yP;
  yE[base + P1 + q] = 0.5f * cc * yR;
  vb[(size_t)bn * P1 + q] = bf16r(gate[b] * cc * yR);
}

// ---------------- K12: wb = bf16(gate*(y - x - u@E^T)) ----------------
__global__ __launch_bounds__(256) void k_w(const float* __restrict__ u, const float* __restrict__ E,
                                           const float* __restrict__ x, const float* __restrict__ gate,
                                           const float* __restrict__ y, short* __restrict__ wb) {
  int b = blockIdx.z;
  int n0 = blockIdx.x * 64, d0 = blockIdx.y * 64;
  const float* ub = u + (size_t)b * N_ * P2;
  __shared__ float As[16][65], Bs[16][65];
  int t = threadIdx.x;
  int tx = t & 15, ty = t >> 4;
  float acc[4][4] = {};
  for (int q0 = 0; q0 < P2; q0 += 16) {
    for (int idx = t; idx < 1024; idx += 256) {
      int nn = idx >> 4, qq = idx & 15;
      As[qq][nn] = ub[(size_t)(n0 + nn) * P2 + q0 + qq];
    }
    for (int idx = t; idx < 1024; idx += 256) {
      int dd = idx >> 4, qq = idx & 15;
      Bs[qq][dd] = E[(size_t)(d0 + dd) * P2 + q0 + qq];
    }
    __syncthreads();
#pragma unroll
    for (int qq = 0; qq < 16; ++qq) {
      float a[4], bv[4];
#pragma unroll
      for (int u2 = 0; u2 < 4; ++u2) a[u2] = As[qq][ty * 4 + u2];
#pragma unroll
      for (int v2 = 0; v2 < 4; ++v2) bv[v2] = Bs[qq][tx * 4 + v2];
#pragma unroll
      for (int u2 = 0; u2 < 4; ++u2)
#pragma unroll
        for (int v2 = 0; v2 < 4; ++v2) acc[u2][v2] = fmaf(a[u2], bv[v2], acc[u2][v2]);
    }
    __syncthreads();
  }
  float gt = gate[b];
#pragma unroll
  for (int u2 = 0; u2 < 4; ++u2)
#pragma unroll
    for (int v2 = 0; v2 < 4; ++v2) {
      size_t gi = ((size_t)b * N_ + n0 + ty * 4 + u2) * DIN + d0 + tx * 4 + v2;
      wb[gi] = bf16r(gt * (y[gi] - x[gi] - acc[u2][v2]));
    }
}

// ---------------- K13: MFMA fused output GEMM: out = [xb|wb|vb] @ Bcat^T + bias ----------------
// 128x128 tile, BK=32, 4 waves (2x2), mfma_f32_16x16x32_bf16, reg-staged dbuf LDS.
__global__ __launch_bounds__(256) void k_final(
    const short* __restrict__ xb, const short* __restrict__ wb, const short* __restrict__ vb,
    const short* __restrict__ Bcat, const float* __restrict__ bias, float* __restrict__ out) {
  __shared__ short As[2][4096];
  __shared__ short Bs[2][4096];
  int t = threadIdx.x;
  int c0 = blockIdx.x * 128;
  int r0 = blockIdx.y * 128;
  int l = t & 63, wid = t >> 6;
  int wr = wid >> 1, wc = wid & 1;
  int fr = l & 15, fq = l >> 4;
  f32x4 acc[4][4] = {};
  short8 ra0, ra1, rb0, rb1;
  const int row0 = t >> 2, c8 = t & 3;
  const int row1 = row0 + 64;
  // prologue: tile 0 (k0=0 -> xb segment)
  ra0 = *(const short8*)(xb + (size_t)(r0 + row0) * 512 + c8 * 8);
  ra1 = *(const short8*)(xb + (size_t)(r0 + row1) * 512 + c8 * 8);
  rb0 = *(const short8*)(Bcat + (size_t)(c0 + row0) * 1216 + c8 * 8);
  rb1 = *(const short8*)(Bcat + (size_t)(c0 + row1) * 1216 + c8 * 8);
  *(short8*)&As[0][row0 * 32 + c8 * 8] = ra0;
  *(short8*)&As[0][row1 * 32 + c8 * 8] = ra1;
  *(short8*)&Bs[0][row0 * 32 + c8 * 8] = rb0;
  *(short8*)&Bs[0][row1 * 32 + c8 * 8] = rb1;
  __syncthreads();
  for (int kt = 0; kt < 38; ++kt) {
    int cur = kt & 1;
    if (kt + 1 < 38) {
      int k0 = (kt + 1) * 32;
      const short* Ap; int aksz, akloc;
      if (k0 < 512)       { Ap = xb; aksz = 512; akloc = k0; }
      else if (k0 < 1024) { Ap = wb; aksz = 512; akloc = k0 - 512; }
      else                { Ap = vb; aksz = 192; akloc = k0 - 1024; }
      ra0 = *(const short8*)(Ap + (size_t)(r0 + row0) * aksz + akloc + c8 * 8);
      ra1 = *(const short8*)(Ap + (size_t)(r0 + row1) * aksz + akloc + c8 * 8);
      rb0 = *(const short8*)(Bcat + (size_t)(c0 + row0) * 1216 + k0 + c8 * 8);
      rb1 = *(const short8*)(Bcat + (size_t)(c0 + row1) * 1216 + k0 + c8 * 8);
    }
    short8 af[4], bf[4];
#pragma unroll
    for (int m = 0; m < 4; ++m)
      af[m] = *(const short8*)&As[cur][(wr * 64 + m * 16 + fr) * 32 + fq * 8];
#pragma unroll
    for (int n = 0; n < 4; ++n)
      bf[n] = *(const short8*)&Bs[cur][(wc * 64 + n * 16 + fr) * 32 + fq * 8];
#pragma unroll
    for (int m = 0; m < 4; ++m)
#pragma unroll
      for (int n = 0; n < 4; ++n)
        acc[m][n] = __builtin_amdgcn_mfma_f32_16x16x32_bf16(af[m], bf[n], acc[m][n], 0, 0, 0);
    __syncthreads();
    if (kt + 1 < 38) {
      int nxt = cur ^ 1;
      *(short8*)&As[nxt][row0 * 32 + c8 * 8] = ra0;
      *(short8*)&As[nxt][row1 * 32 + c8 * 8] = ra1;
      *(short8*)&Bs[nxt][row0 * 32 + c8 * 8] = rb0;
      *(short8*)&Bs[nxt][row1 * 32 + c8 * 8] = rb1;
    }
    __syncthreads();
  }
#pragma unroll
  for (int n = 0; n < 4; ++n) {
    int col = c0 + wc * 64 + n * 16 + fr;
    float bv = bias[col];
#pragma unroll
    for (int m = 0; m < 4; ++m) {
      int rbase = r0 + wr * 64 + m * 16 + fq * 4;
#pragma unroll
      for (int j = 0; j < 4; ++j)
        out[(size_t)(rbase + j) * DOUT + col] = acc[m][n][j] + bv;
    }
  }
}

extern "C" void kernel_launch(void* const* d_in, const int* in_sizes, int n_in,
                              void* d_out, int out_size, void* d_ws, size_t ws_size,
                              hipStream_t stream) {
  (void)in_sizes; (void)n_in; (void)out_size; (void)ws_size;
  const float* x     = (const float*)d_in[0];
  const float* Wsh   = (const float*)d_in[1];
  const float* bias  = (const float*)d_in[2];
  const float* U0    = (const float*)d_in[3];
  const float* leftb = (const float*)d_in[4];
  const float* rightb= (const float*)d_in[5];
  const float* W1    = (const float*)d_in[6];
  const float* b1    = (const float*)d_in[7];
  const float* Wc    = (const float*)d_in[8];
  const float* bc    = (const float*)d_in[9];
  const float* Wg    = (const float*)d_in[10];
  const float* bg    = (const float*)d_in[11];
  float* out = (float*)d_out;

  float* wsf = (float*)d_ws;
  // fixed layout (floats), all offsets 64-aligned; total ~49.8 MB
  float* z     = wsf + 0;         // 49152
  float* coeff = wsf + 49152;     // 512
  float* gate  = wsf + 49664;     // 64
  float* norms = wsf + 49728;     // 64
  float* cp    = wsf + 49792;     // 512
  float* LcatF = wsf + 50304;     // 393216
  float* E     = wsf + 443520;    // 196608
  float* GLL   = wsf + 640128;    // 36864
  float* GE    = wsf + 676992;    // 147456
  float* M0    = wsf + 824448;    // 147456
  float* y     = wsf + 971904;    // 4194304
  float* yE    = wsf + 5166208;   // 3145728
  float* Wd    = wsf + 7263360;   // 1048576 (aliases yE tail; dead before k_yE)
  short* wb    = (short*)(wsf + 8311936);   // 4194304 shorts
  short* vb    = (short*)(wsf + 10409088);  // 1572864 shorts
  short* Bcat  = (short*)(wsf + 11195520);  // 2490368 shorts
  // H aliases [y .. y+6291456) — dead before y is written by k_tri2
  float* H = y;
  // xb (bf16 of x) aliases the y region — written after k_w (y dead by then)
  short* xbuf = (short*)y;
  // G lives in d_out; fully overwritten by k_final
  float* G = out;

  k_stats<<<B_, DIN, 0, stream>>>(x, z);
  k_controller<<<B_, HC, 0, stream>>>(z, W1, b1, Wc, bc, Wg, bg, coeff, gate);
  k_copy_bases<<<(DOUT * P1 + DIN * P1 + 255) / 256, 256, 0, stream>>>(leftb, rightb, LcatF, E);
  k_pack_B<<<(DOUT * 152 + 255) / 256, 256, 0, stream>>>(Wsh, U0, LcatF, Bcat);
  k_gemm_tn<<<dim3(DIN / 32, P1 / 32), 256, 0, stream>>>(U0, LcatF, E + P1, DIN, P1, DOUT, DIN, P1, P2);
  k_gemm_tn<<<dim3(P1 / 32, P1 / 32), 256, 0, stream>>>(LcatF, LcatF, GLL, P1, P1, DOUT, P1, P1, P1);
  k_gemm_tn<<<dim3(P2 / 32, P2 / 32), 256, 0, stream>>>(E, E, GE, P2, P2, DIN, P2, P2, P2);
  k_norms<<<K_, 64, 0, stream>>>(GLL, GE, norms);
  k_cprime<<<1, 512, 0, stream>>>(coeff, norms, cp);
  k_m0<<<(P2 * P2 + 255) / 256, 256, 0, stream>>>(GLL, GE, M0);
  k_H<<<dim3(DIN / 64, P2 / 64, B_), 256, 0, stream>>>(E, M0, cp, H);
  k_G<<<dim3(DIN / 64, DIN / 64, B_), 256, 0, stream>>>(H, E, cp, G);
  for (int p = 0; p < 8; ++p) {
    int j0 = p * 64;
    int nt = 7 - p;
    k_chol_dp<<<dim3(nt + 1, B_), 64, 0, stream>>>(G, j0);
    if (nt > 0)
      k_chol_tr<<<dim3(nt * (nt + 1) / 2, B_), 256, 0, stream>>>(G, j0, nt);
  }
  k_tinv_diag<<<dim3(8, B_), 64, 0, stream>>>(G, Wd);
  for (int p = 7; p >= 0; --p)
    k_tri2<<<dim3(N_ / 64, B_), 256, 0, stream>>>(x, G, Wd, y, p * 64);
  k_yE<<<dim3(N_ / 64, P2 / 64, B_), 256, 0, stream>>>(y, E, yE);
  k_uv<<<(B_ * N_ * P1 + 255) / 256, 256, 0, stream>>>(cp, gate, yE, vb);
  k_w<<<dim3(N_ / 64, DIN / 64, B_), 256, 0, stream>>>(yE, E, x, gate, y, wb);
  k_pack_x<<<(B_ * N_ * DIN / 8 + 255) / 256, 256, 0, stream>>>(x, xbuf);
  k_final<<<dim3(DOUT / 128, (B_ * N_) / 128), 256, 0, stream>>>(xbuf, wb, vb, Bcat, bias, out);
}